// Round 1
// 1150.384 us; speedup vs baseline: 1.4603x; 1.4603x over previous
//
#include <hip/hip_runtime.h>
#include <math.h>

// WaveNet forward, round 5: occupancy push.
// - Layer kernel LDS cut 51200 -> 34816 B: X split into two 64x136 tap
//   buffers (tap0 = t-d rows, tap1 = t rows). After the conv GEMM the tap0
//   buffer is dead (residual only needs tap1), so G (gated, 64x136) ALIASES
//   the tap0 buffer. One extra __syncthreads() between conv reads and GLU
//   writes. 160KB/34816 = 4 blocks/CU, matching the 4-blocks/CU grid
//   (1024 blocks / 256 CUs). __launch_bounds__(256,4).
// - Everything else (layouts, prep, front, head) unchanged from round 4:
//   h ping-pong f16 [n][t][c]; skip accum fused as f16 frag-linear chunk RMW;
//   head: chunk -> relu -> a_w -> relu -> b_w -> logits.
//
// MFMA 16x16x32_f16: A lane: A[m=lane&15][k=(lane>>4)*8+j]; D lane:
// D[row=(lane>>4)*4+reg][col=lane&15]. Conv A-rows interleaved (a0,b0,a1,b1..)
// so GLU happens in registers. Conv K order: k = tap*128 + c.

#define NB 4
#define WLEN 16384
#define C 128
#define S 256
#define NLAYERS 30
#define TT 64
#define NTB (WLEN / TT)   // 256 tiles per sample
#define XROW 264          // head X row stride (f16): 256 + 8 pad
#define GROW 136          // layer tile row stride (f16): 128 + 8 pad

typedef _Float16 half8 __attribute__((ext_vector_type(8)));
typedef _Float16 half4 __attribute__((ext_vector_type(4)));
typedef float floatx4 __attribute__((ext_vector_type(4)));

__device__ __forceinline__ float sigmoidf_(float v) {
    return 1.0f / (1.0f + __expf(-v));
}

// ---------------- weight packing ----------------
// cw : conv, per layer M=256 rows interleaved (m'=2r+s: s=0 a-row r, s=1 b-row r+128),
//      K=256 with k = tap*128 + c. Frag-linear [mt][ks][lane][8].
// rsw: res  M=128 K=128; skw: skip M=256 K=128; aw/bw: 256x256.
// cbp: conv bias interleaved; ssum: sum over layers of skip_b.
__global__ void prep_kernel(const float* __restrict__ conv_w,
                            const float* __restrict__ res_w,
                            const float* __restrict__ skip_w,
                            const float* __restrict__ a_w,
                            const float* __restrict__ b_w,
                            const float* __restrict__ conv_b,
                            const float* __restrict__ skip_b,
                            _Float16* __restrict__ cw,
                            _Float16* __restrict__ rsw,
                            _Float16* __restrict__ skw,
                            _Float16* __restrict__ aw,
                            _Float16* __restrict__ bw,
                            float* __restrict__ cbp,
                            float* __restrict__ ssum) {
    const int ncw = NLAYERS * 256 * 256;
    const int nrs = NLAYERS * 128 * 128;
    const int nsk = NLAYERS * 256 * 128;
    const int nab = 256 * 256;
    const int ncb = NLAYERS * 256;
    const int total = ncw + nrs + nsk + nab + nab + ncb + 256;
    for (int idx = blockIdx.x * blockDim.x + threadIdx.x; idx < total;
         idx += gridDim.x * blockDim.x) {
        int i = idx;
        if (i < ncw) {
            int j = i & 7, lane = (i >> 3) & 63, rest = i >> 9;
            int ks = rest & 7; rest >>= 3;
            int mt = rest & 15; int l = rest >> 4;
            int mp = mt * 16 + (lane & 15);
            int orow = (mp >> 1) + (mp & 1) * 128;
            int k = ks * 32 + (lane >> 4) * 8 + j;
            int tap = k >> 7, c = k & 127;
            cw[i] = (_Float16)conv_w[(((size_t)l * 256 + orow) * 128 + c) * 2 + tap];
        } else if (i < ncw + nrs) {
            i -= ncw;
            int j = i & 7, lane = (i >> 3) & 63, rest = i >> 9;
            int ks = rest & 3; rest >>= 2;
            int mt = rest & 7; int l = rest >> 3;
            int m = mt * 16 + (lane & 15);
            int k = ks * 32 + (lane >> 4) * 8 + j;
            rsw[i] = (_Float16)res_w[((size_t)l * 128 + m) * 128 + k];
        } else if (i < ncw + nrs + nsk) {
            i -= ncw + nrs;
            int j = i & 7, lane = (i >> 3) & 63, rest = i >> 9;
            int ks = rest & 3; rest >>= 2;
            int mt = rest & 15; int l = rest >> 4;
            int m = mt * 16 + (lane & 15);
            int k = ks * 32 + (lane >> 4) * 8 + j;
            skw[i] = (_Float16)skip_w[((size_t)l * 256 + m) * 128 + k];
        } else if (i < ncw + nrs + nsk + nab) {
            i -= ncw + nrs + nsk;
            int j = i & 7, lane = (i >> 3) & 63, rest = i >> 9;
            int ks = rest & 7; int mt = rest >> 3;
            aw[i] = (_Float16)a_w[(mt * 16 + (lane & 15)) * 256 + ks * 32 + (lane >> 4) * 8 + j];
        } else if (i < ncw + nrs + nsk + 2 * nab) {
            i -= ncw + nrs + nsk + nab;
            int j = i & 7, lane = (i >> 3) & 63, rest = i >> 9;
            int ks = rest & 7; int mt = rest >> 3;
            bw[i] = (_Float16)b_w[(mt * 16 + (lane & 15)) * 256 + ks * 32 + (lane >> 4) * 8 + j];
        } else if (i < ncw + nrs + nsk + 2 * nab + ncb) {
            i -= ncw + nrs + nsk + 2 * nab;
            int mp = i & 255; int l = i >> 8;
            cbp[i] = conv_b[l * 256 + (mp >> 1) + (mp & 1) * 128];
        } else {
            i -= ncw + nrs + nsk + 2 * nab + ncb;
            float s = 0.f;
            for (int l = 0; l < NLAYERS; ++l) s += skip_b[l * 256 + i];
            ssum[i] = s;
        }
    }
}

// ---------------- front: h0 (f16, [n][t][c]) ----------------
__global__ void front_kernel(const float* __restrict__ x,
                             const float* __restrict__ w_shift,
                             const float* __restrict__ b_shift,
                             _Float16* __restrict__ h) {
    const int n = blockIdx.y;
    const int t = blockIdx.x * 256 + threadIdx.x;
    float x1 = (t >= 1) ? x[n * WLEN + t - 1] : 0.0f;
    float x2 = (t >= 2) ? x[n * WLEN + t - 2] : 0.0f;
    _Float16* hq = h + ((size_t)n * WLEN + t) * 128;
    #pragma unroll
    for (int c0 = 0; c0 < 128; c0 += 8) {
        half8 v;
        #pragma unroll
        for (int j = 0; j < 8; ++j) {
            int c = c0 + j;
            v[j] = (_Float16)fmaf(w_shift[2 * c], x2,
                                  fmaf(w_shift[2 * c + 1], x1, b_shift[c]));
        }
        *(half8*)&hq[c0] = v;
    }
}

// ---------------- one residual layer (conv + GLU + skip-RMW + res) ----------------
template <bool FIRST>
__global__ __launch_bounds__(256, 4) void layer_kernel(
    const _Float16* __restrict__ h_in, _Float16* __restrict__ h_out,
    _Float16* __restrict__ chunk,
    const _Float16* __restrict__ cw, const float* __restrict__ cb,
    const _Float16* __restrict__ rsw, const float* __restrict__ rb,
    const _Float16* __restrict__ skw, const float* __restrict__ ssum, int d) {
    // X0: tap0 rows (t-d), X1: tap1 rows (t). G aliases X0 after conv GEMM.
    __shared__ _Float16 SMEM[2 * TT * GROW];  // 34816 B -> 4 blocks/CU
    _Float16* X0 = SMEM;
    _Float16* X1 = SMEM + TT * GROW;
    _Float16* G  = X0;  // alias: tap0 dead after conv reads
    const int n = blockIdx.y, tb = blockIdx.x, t0 = tb * TT;
    const int tid = threadIdx.x;
    const int wave = __builtin_amdgcn_readfirstlane(tid >> 6);
    const int lane = tid & 63, q = lane >> 4, ml = lane & 15;

    // ---- stage both taps: contiguous 16B row-segment copies
    const _Float16* hn = h_in + (size_t)n * WLEN * 128;
    #pragma unroll
    for (int it = 0; it < 8; ++it) {
        int idx = it * 256 + tid;        // 0..2047
        int seg = idx & 15;              // 16B segment (8 f16)
        int rowc = (idx >> 4) & 63;      // dest row (t within tile)
        int tap = idx >> 10;             // 0: t-d, 1: t
        int src_t = t0 + rowc - (tap ? 0 : d);
        half8 v = (half8)(_Float16)0.0f;
        if (src_t >= 0)
            v = *(const half8*)&hn[(size_t)src_t * 128 + seg * 8];
        _Float16* Xb = tap ? X1 : X0;
        *(half8*)&Xb[rowc * GROW + seg * 8] = v;
    }
    __syncthreads();

    // ---- conv GEMM (interleaved rows): D[m'][t], K=256 (k = tap*128 + c)
    floatx4 acc[4][4];
    #pragma unroll
    for (int mt = 0; mt < 4; ++mt)
        #pragma unroll
        for (int r = 0; r < 4; ++r) {
            float bias = cb[64 * wave + mt * 16 + q * 4 + r];
            #pragma unroll
            for (int nt = 0; nt < 4; ++nt) acc[mt][nt][r] = bias;
        }
    #pragma unroll
    for (int half = 0; half < 2; ++half) {
        const _Float16* Xb = half ? X1 : X0;
        for (int ks = 0; ks < 4; ++ks) {
            half8 b[4];
            #pragma unroll
            for (int nt = 0; nt < 4; ++nt)
                b[nt] = *(const half8*)&Xb[(nt * 16 + ml) * GROW + ks * 32 + q * 8];
            #pragma unroll
            for (int mt = 0; mt < 4; ++mt) {
                half8 a = *(const half8*)&cw[((((4 * wave + mt) * 8) + half * 4 + ks) * 64 + lane) * 8];
                #pragma unroll
                for (int nt = 0; nt < 4; ++nt)
                    acc[mt][nt] = __builtin_amdgcn_mfma_f32_16x16x32_f16(a, b[nt], acc[mt][nt], 0, 0, 0);
            }
        }
    }
    __syncthreads();  // all conv reads of X0 done before G overwrites it

    // ---- GLU in registers -> G[t][r] (aliases X0; X1 keeps residual taps)
    #pragma unroll
    for (int mt = 0; mt < 4; ++mt)
        #pragma unroll
        for (int nt = 0; nt < 4; ++nt) {
            float g0 = acc[mt][nt][0] * sigmoidf_(acc[mt][nt][1]);
            float g1 = acc[mt][nt][2] * sigmoidf_(acc[mt][nt][3]);
            _Float16 p[2] = {(_Float16)g0, (_Float16)g1};
            *(uint32_t*)&G[(nt * 16 + ml) * GROW + 32 * wave + mt * 8 + 2 * q] = *(uint32_t*)p;
        }
    __syncthreads();

    // ---- skip GEMM (M=256, wave owns mtiles 4w..4w+3) + f16 frag-linear RMW
    {
        floatx4 sacc[4][4];
        #pragma unroll
        for (int mt = 0; mt < 4; ++mt)
            #pragma unroll
            for (int r = 0; r < 4; ++r) {
                float bias = FIRST ? ssum[64 * wave + mt * 16 + q * 4 + r] : 0.0f;
                #pragma unroll
                for (int nt = 0; nt < 4; ++nt) sacc[mt][nt][r] = bias;
            }
        #pragma unroll
        for (int ks = 0; ks < 4; ++ks) {
            half8 b[4];
            #pragma unroll
            for (int nt = 0; nt < 4; ++nt)
                b[nt] = *(const half8*)&G[(nt * 16 + ml) * GROW + ks * 32 + q * 8];
            #pragma unroll
            for (int mt = 0; mt < 4; ++mt) {
                half8 a = *(const half8*)&skw[((((4 * wave + mt) * 4) + ks) * 64 + lane) * 8];
                #pragma unroll
                for (int nt = 0; nt < 4; ++nt)
                    sacc[mt][nt] = __builtin_amdgcn_mfma_f32_16x16x32_f16(a, b[nt], sacc[mt][nt], 0, 0, 0);
            }
        }
        _Float16* cp = chunk + ((size_t)n * NTB + tb) * 16384;
        #pragma unroll
        for (int mt = 0; mt < 4; ++mt)
            #pragma unroll
            for (int nt = 0; nt < 4; ++nt) {
                size_t o = (size_t)((((wave * 4 + mt) * 4) + nt) * 64 + lane) * 4;
                if (FIRST) {
                    half4 v;
                    #pragma unroll
                    for (int r = 0; r < 4; ++r) v[r] = (_Float16)sacc[mt][nt][r];
                    *(half4*)&cp[o] = v;
                } else {
                    half4 v = *(const half4*)&cp[o];
                    half4 w;
                    #pragma unroll
                    for (int r = 0; r < 4; ++r)
                        w[r] = (_Float16)(sacc[mt][nt][r] + (float)v[r]);
                    *(half4*)&cp[o] = w;
                }
            }
    }

    // ---- res GEMM (M=128, wave owns mtiles 2w,2w+1) + residual add
    {
        floatx4 racc[2][4];
        #pragma unroll
        for (int mt = 0; mt < 2; ++mt)
            #pragma unroll
            for (int r = 0; r < 4; ++r) {
                float bias = rb[32 * wave + mt * 16 + q * 4 + r];
                #pragma unroll
                for (int nt = 0; nt < 4; ++nt) racc[mt][nt][r] = bias;
            }
        #pragma unroll
        for (int ks = 0; ks < 4; ++ks) {
            half8 b[4];
            #pragma unroll
            for (int nt = 0; nt < 4; ++nt)
                b[nt] = *(const half8*)&G[(nt * 16 + ml) * GROW + ks * 32 + q * 8];
            #pragma unroll
            for (int mt = 0; mt < 2; ++mt) {
                half8 a = *(const half8*)&rsw[((((2 * wave + mt) * 4) + ks) * 64 + lane) * 8];
                #pragma unroll
                for (int nt = 0; nt < 4; ++nt)
                    racc[mt][nt] = __builtin_amdgcn_mfma_f32_16x16x32_f16(a, b[nt], racc[mt][nt], 0, 0, 0);
            }
        }
        _Float16* ho = h_out + (size_t)n * WLEN * 128;
        #pragma unroll
        for (int mt = 0; mt < 2; ++mt)
            #pragma unroll
            for (int nt = 0; nt < 4; ++nt) {
                int tt = nt * 16 + ml;
                int c = 32 * wave + mt * 16 + q * 4;
                half4 hv = *(const half4*)&X1[tt * GROW + c];  // tap1 = h_in(c,t)
                half4 o;
                #pragma unroll
                for (int r = 0; r < 4; ++r)
                    o[r] = (_Float16)(racc[mt][nt][r] + (float)hv[r]);
                *(half4*)&ho[(size_t)(t0 + tt) * 128 + c] = o;
            }
    }
}

// ---------------- head: chunk -> relu -> a_w -> relu -> b_w -> logits ----------------
__global__ __launch_bounds__(256, 4) void head_kernel(
    float* __restrict__ out, const _Float16* __restrict__ chunk,
    const _Float16* __restrict__ aw, const float* __restrict__ ab,
    const _Float16* __restrict__ bw, const float* __restrict__ bb) {
    __shared__ _Float16 X[TT * XROW];
    const int n = blockIdx.y, tb = blockIdx.x, t0 = tb * TT;
    const int tid = threadIdx.x;
    const int wave = __builtin_amdgcn_readfirstlane(tid >> 6);
    const int lane = tid & 63, q = lane >> 4, ml = lane & 15;

    // ---- z = relu(skips) from frag-linear chunk -> X[t][s]
    {
        const _Float16* cp = chunk + ((size_t)n * NTB + tb) * 16384;
        #pragma unroll
        for (int mt = 0; mt < 4; ++mt)
            #pragma unroll
            for (int nt = 0; nt < 4; ++nt) {
                size_t o = (size_t)((((wave * 4 + mt) * 4) + nt) * 64 + lane) * 4;
                half4 v = *(const half4*)&cp[o];
                half4 z;
                #pragma unroll
                for (int r = 0; r < 4; ++r)
                    z[r] = (_Float16)fmaxf((float)v[r], 0.0f);
                *(half4*)&X[(nt * 16 + ml) * XROW + 64 * wave + mt * 16 + q * 4] = z;
            }
    }
    __syncthreads();

    floatx4 acc[4][4];
    // ---- z2 = relu(a_w @ z + a_b)
    #pragma unroll
    for (int mt = 0; mt < 4; ++mt)
        #pragma unroll
        for (int r = 0; r < 4; ++r) {
            float bias = ab[64 * wave + mt * 16 + q * 4 + r];
            #pragma unroll
            for (int nt = 0; nt < 4; ++nt) acc[mt][nt][r] = bias;
        }
    for (int ks = 0; ks < 8; ++ks) {
        half8 b[4];
        #pragma unroll
        for (int nt = 0; nt < 4; ++nt)
            b[nt] = *(const half8*)&X[(nt * 16 + ml) * XROW + ks * 32 + q * 8];
        #pragma unroll
        for (int mt = 0; mt < 4; ++mt) {
            half8 a = *(const half8*)&aw[((((4 * wave + mt) * 8) + ks) * 64 + lane) * 8];
            #pragma unroll
            for (int nt = 0; nt < 4; ++nt)
                acc[mt][nt] = __builtin_amdgcn_mfma_f32_16x16x32_f16(a, b[nt], acc[mt][nt], 0, 0, 0);
        }
    }
    __syncthreads();
    #pragma unroll
    for (int mt = 0; mt < 4; ++mt)
        #pragma unroll
        for (int nt = 0; nt < 4; ++nt) {
            half4 z;
            #pragma unroll
            for (int r = 0; r < 4; ++r)
                z[r] = (_Float16)fmaxf(acc[mt][nt][r], 0.0f);
            *(half4*)&X[(nt * 16 + ml) * XROW + 64 * wave + mt * 16 + q * 4] = z;
        }
    __syncthreads();

    // ---- logits = b_w @ z2 + b_b
    #pragma unroll
    for (int mt = 0; mt < 4; ++mt)
        #pragma unroll
        for (int r = 0; r < 4; ++r) {
            float bias = bb[64 * wave + mt * 16 + q * 4 + r];
            #pragma unroll
            for (int nt = 0; nt < 4; ++nt) acc[mt][nt][r] = bias;
        }
    for (int ks = 0; ks < 8; ++ks) {
        half8 b[4];
        #pragma unroll
        for (int nt = 0; nt < 4; ++nt)
            b[nt] = *(const half8*)&X[(nt * 16 + ml) * XROW + ks * 32 + q * 8];
        #pragma unroll
        for (int mt = 0; mt < 4; ++mt) {
            half8 a = *(const half8*)&bw[((((4 * wave + mt) * 8) + ks) * 64 + lane) * 8];
            #pragma unroll
            for (int nt = 0; nt < 4; ++nt)
                acc[mt][nt] = __builtin_amdgcn_mfma_f32_16x16x32_f16(a, b[nt], acc[mt][nt], 0, 0, 0);
        }
    }
    float* on = out + (size_t)n * S * WLEN;
    #pragma unroll
    for (int mt = 0; mt < 4; ++mt)
        #pragma unroll
        for (int nt = 0; nt < 4; ++nt)
            #pragma unroll
            for (int r = 0; r < 4; ++r) {
                int o = 64 * wave + mt * 16 + q * 4 + r;
                int tt = t0 + nt * 16 + ml;
                on[(size_t)o * WLEN + tt] = acc[mt][nt][r];
            }
}

extern "C" void kernel_launch(void* const* d_in, const int* in_sizes, int n_in,
                              void* d_out, int out_size, void* d_ws, size_t ws_size,
                              hipStream_t stream) {
    (void)in_sizes; (void)n_in; (void)out_size; (void)ws_size;
    const float* x       = (const float*)d_in[0];
    const float* w_shift = (const float*)d_in[1];
    const float* b_shift = (const float*)d_in[2];
    const float* conv_w  = (const float*)d_in[3];
    const float* conv_b  = (const float*)d_in[4];
    const float* res_w   = (const float*)d_in[5];
    const float* res_b   = (const float*)d_in[6];
    const float* skip_w  = (const float*)d_in[7];
    const float* skip_b  = (const float*)d_in[8];
    const float* a_w     = (const float*)d_in[9];
    const float* a_b     = (const float*)d_in[10];
    const float* b_w     = (const float*)d_in[11];
    const float* b_b     = (const float*)d_in[12];
    float* out = (float*)d_out;

    char* ws = (char*)d_ws;
    size_t off = 0;
    _Float16* hA    = (_Float16*)(ws + off); off += (size_t)NB * WLEN * 128 * 2;
    _Float16* hB    = (_Float16*)(ws + off); off += (size_t)NB * WLEN * 128 * 2;
    _Float16* chunk = (_Float16*)(ws + off); off += (size_t)NB * NTB * 16384 * 2;
    _Float16* cw  = (_Float16*)(ws + off); off += (size_t)NLAYERS * 256 * 256 * 2;
    _Float16* rsw = (_Float16*)(ws + off); off += (size_t)NLAYERS * 128 * 128 * 2;
    _Float16* skw = (_Float16*)(ws + off); off += (size_t)NLAYERS * 256 * 128 * 2;
    _Float16* aw  = (_Float16*)(ws + off); off += 256 * 256 * 2;
    _Float16* bw  = (_Float16*)(ws + off); off += 256 * 256 * 2;
    float* cbp  = (float*)(ws + off); off += (size_t)NLAYERS * 256 * 4;
    float* ssum = (float*)(ws + off); off += 256 * 4;
    // total ~74.3 MB

    prep_kernel<<<512, 256, 0, stream>>>(conv_w, res_w, skip_w, a_w, b_w,
                                         conv_b, skip_b,
                                         cw, rsw, skw, aw, bw, cbp, ssum);
    front_kernel<<<dim3(WLEN / 256, NB), 256, 0, stream>>>(x, w_shift, b_shift, hA);

    const dim3 grid(NTB, NB);
    _Float16* hin = hA;
    _Float16* hout = hB;
    for (int l = 0; l < NLAYERS; ++l) {
        int dil = 1 << (l % 10);
        const _Float16* cwp = cw + (size_t)l * 65536;
        const _Float16* rsp = rsw + (size_t)l * 16384;
        const _Float16* skp = skw + (size_t)l * 32768;
        if (l == 0)
            layer_kernel<true><<<grid, 256, 0, stream>>>(
                hin, hout, chunk, cwp, cbp + l * 256,
                rsp, res_b + l * 128, skp, ssum, dil);
        else
            layer_kernel<false><<<grid, 256, 0, stream>>>(
                hin, hout, chunk, cwp, cbp + l * 256,
                rsp, res_b + l * 128, skp, ssum, dil);
        _Float16* tmp = hin; hin = hout; hout = tmp;
    }

    head_kernel<<<grid, 256, 0, stream>>>(out, chunk, aw, a_b, bw, b_b);
}